// Round 15
// baseline (442.728 us; speedup 1.0000x reference)
//
#include <hip/hip_runtime.h>
#include <hip/hip_bf16.h>
#include <hip/hip_fp16.h>

#define GN 100000
#define GE 600000
#define SCAN_NBLK 98   // ceil(GN / 1024)
#define ALD 132        // fp32 LDS leading dim: 128 + 4
#define EDGE_BLOCKS ((GE + 255) / 256)      // 2344
#define CONV_BLOCKS ((81984 + 255) / 256)   // 321

typedef __bf16    bf16x8 __attribute__((ext_vector_type(8)));
typedef _Float16  f16x8  __attribute__((ext_vector_type(8)));
typedef float     f32x4  __attribute__((ext_vector_type(4)));

// ---------------------------------------------------------------------------
// FUSED preamble kernel: blocks [0, EDGE_BLOCKS) count degrees (atomicAdd);
// blocks [EDGE_BLOCKS, EDGE_BLOCKS+CONV_BLOCKS) do weight conversion + W3p +
// cvec. The two halves are fully independent.
// Plane layout (81920 entries each):
//   [0,16384)      W_in [128,128]
//   [16384,32768)  Wc0  [128,128]
//   [32768,49152)  Wc1  [128,128]
//   [49152,57344)  E0   [64,128] = Wo0 (W_out cols 0-127)
//   [57344,65536)  E1   [64,128] = Wo1 (cols 128-255)
//   [65536,81920)  E2   [128,128]: rows 0-63 = Wo2 (cols 256-383),
//                  rows 64-127 = W3p = Wo3 @ W3
// i in [81920,81984): cvec[i-81920] = Wo3 @ b3 + b_out.
// ---------------------------------------------------------------------------
__global__ __launch_bounds__(256) void prep_fused(
    const int* __restrict__ dst, int* __restrict__ deg,
    const float* __restrict__ Win, const float* __restrict__ Wc,
    const float* __restrict__ Wout,
    const float* __restrict__ b3, const float* __restrict__ bOut,
    __bf16* __restrict__ hi, __bf16* __restrict__ lo,
    float* __restrict__ cvec)
{
    if (blockIdx.x < EDGE_BLOCKS) {
        const int e = blockIdx.x * 256 + threadIdx.x;
        if (e < GE) atomicAdd(&deg[dst[e]], 1);
        return;
    }
    const int i = (blockIdx.x - EDGE_BLOCKS) * 256 + threadIdx.x;
    const float* W3 = Wc + 32768;                    // W_convs[2]
    if (i >= 81984) return;
    if (i >= 81920) {                                // cvec
        const int o = i - 81920;
        float c = bOut[o];
        for (int j = 0; j < 128; ++j)
            c += Wout[o * 512 + 384 + j] * b3[j];
        cvec[o] = c;
        return;
    }
    float v;
    if (i < 16384) {
        v = Win[i];
    } else if (i < 49152) {
        v = Wc[i - 16384];                           // Wc0, Wc1
    } else if (i < 57344) {
        const int j = i - 49152;                     // E0
        v = Wout[(j >> 7) * 512 + (j & 127)];
    } else if (i < 65536) {
        const int j = i - 57344;                     // E1
        v = Wout[(j >> 7) * 512 + 128 + (j & 127)];
    } else if (i < 73728) {
        const int j = i - 65536;                     // E2 rows 0-63
        v = Wout[(j >> 7) * 512 + 256 + (j & 127)];
    } else {
        const int j = i - 65536;                     // E2 rows 64-127 = W3p
        const int o = (j >> 7) - 64;                 // 0..63
        const int k = j & 127;
        float s = 0.f;
        for (int jj = 0; jj < 128; ++jj)
            s += Wout[o * 512 + 384 + jj] * W3[jj * 128 + k];
        v = s;
    }
    const __bf16 h = (__bf16)v;
    hi[i] = h;
    lo[i] = (__bf16)(v - (float)h);
}

// ---------------------------------------------------------------------------
// scan_pass1 with FOLDED scan_pass2: per-block 1024-elem scan writes excl +
// blockSums; the LAST finishing block (atomic done-counter, threadfence on
// both sides) scans the 98 blockSums into blockOffs. No dispatch-order
// assumption -- only "last to finish runs after all writes", guaranteed by
// the device-scope atomic + fences.
// ---------------------------------------------------------------------------
__global__ __launch_bounds__(256) void scan_pass1(const int* __restrict__ deg,
                                                  int* __restrict__ excl,
                                                  int* __restrict__ blockSums,
                                                  int* __restrict__ blockOffs,
                                                  int* __restrict__ done)
{
    __shared__ int s[256];
    __shared__ bool amLast;
    const int t = threadIdx.x;
    const int base = blockIdx.x * 1024 + t * 4;

    int4 v = make_int4(0, 0, 0, 0);
    if (base + 3 < GN) {
        v = *(const int4*)(deg + base);
    } else {
        if (base + 0 < GN) v.x = deg[base + 0];
        if (base + 1 < GN) v.y = deg[base + 1];
        if (base + 2 < GN) v.z = deg[base + 2];
        if (base + 3 < GN) v.w = deg[base + 3];
    }
    const int mysum = v.x + v.y + v.z + v.w;
    s[t] = mysum;
    __syncthreads();
    for (int off = 1; off < 256; off <<= 1) {
        const int val = (t >= off) ? s[t - off] : 0;
        __syncthreads();
        s[t] += val;
        __syncthreads();
    }
    int4 o;
    o.x = s[t] - mysum;
    o.y = o.x + v.x;
    o.z = o.y + v.y;
    o.w = o.z + v.z;
    if (base + 3 < GN) {
        *(int4*)(excl + base) = o;
    } else {
        if (base + 0 < GN) excl[base + 0] = o.x;
        if (base + 1 < GN) excl[base + 1] = o.y;
        if (base + 2 < GN) excl[base + 2] = o.z;
        if (base + 3 < GN) excl[base + 3] = o.w;
    }
    if (t == 255) blockSums[blockIdx.x] = s[255];

    // ---- folded scan_pass2 ----
    __threadfence();
    if (t == 0)
        amLast = (atomicAdd(done, 1) == SCAN_NBLK - 1);
    __syncthreads();
    if (amLast) {
        __threadfence();     // acquire side: make other blocks' sums visible
        const int bv = (t < SCAN_NBLK) ? blockSums[t] : 0;
        s[t] = (t < 128) ? bv : 0;
        __syncthreads();
        for (int off = 1; off < 128; off <<= 1) {
            const int val = (t >= off && t < 128) ? s[t - off] : 0;
            __syncthreads();
            if (t < 128) s[t] += val;
            __syncthreads();
        }
        if (t < SCAN_NBLK) blockOffs[t] = s[t] - bv;
    }
}

// ---------------------------------------------------------------------------
// Streaming gather on fp16 128-dim rows, PRE-ADDED fp32 output:
// Aggp[row] = sum(neighbors) + h[row]. (unchanged)
// ---------------------------------------------------------------------------
__global__ __launch_bounds__(256, 8) void gather_rows(
    const uint* __restrict__ Hw,
    const int* __restrict__ row_start,
    const int* __restrict__ deg,
    const int* __restrict__ csr,
    float* __restrict__ Aggp)
{
    const int wave = threadIdx.x >> 6;
    const int lane = threadIdx.x & 63;
    const int row  = blockIdx.x * 4 + wave;
    if (row >= GN) return;

    const uint self = Hw[(size_t)row * 64 + lane];
    const int start = row_start[row];
    const int dg    = deg[row];
    float2 acc = make_float2(0.f, 0.f);

    for (int b = 0; b < dg; b += 64) {
        const int n = min(dg - b, 64);
        const int idx = csr[start + min(b + lane, dg - 1)];
        for (int k = 0; k < n; k += 8) {
            uint t[8];
#pragma unroll
            for (int u = 0; u < 8; ++u) {
                const int s = __shfl(idx, min(k + u, n - 1));
                t[u] = Hw[(size_t)s * 64 + lane];
            }
            const int m = min(n - k, 8);
#pragma unroll
            for (int u = 0; u < 8; ++u) {
                if (u < m) {
                    union { uint uu; _Float16 h[2]; } cv;
                    cv.uu = t[u];
                    acc.x += (float)cv.h[0];
                    acc.y += (float)cv.h[1];
                }
            }
        }
    }

    union { uint uu; _Float16 h[2]; } sv;
    sv.uu = self;
    acc.x += (float)sv.h[0];
    acc.y += (float)sv.h[1];

    *(float2*)&Aggp[(size_t)row * 128 + lane * 2] = acc;
}

// ---------------------------------------------------------------------------
// FUSED final: gather y2 neighbors + self, add p0+p1+p2+cvec, softmax -> out.
// (unchanged)
// ---------------------------------------------------------------------------
__global__ __launch_bounds__(256, 8) void gather_softmax(
    const float* __restrict__ Y,               // y2 [GN,64]
    const int* __restrict__ row_start,
    const int* __restrict__ deg,
    const int* __restrict__ csr,
    const float* __restrict__ P0,
    const float* __restrict__ P1,
    const float* __restrict__ P2,
    const float* __restrict__ cvec,
    float* __restrict__ out)
{
    const int wave = threadIdx.x >> 6;
    const int lane = threadIdx.x & 63;
    const int row  = blockIdx.x * 4 + wave;
    if (row >= GN) return;

    const size_t g = (size_t)row * 64 + lane;
    const float p0 = P0[g];
    const float p1 = P1[g];
    const float p2 = P2[g];
    const float self = Y[g];
    const float cv = cvec[lane];

    const int start = row_start[row];
    const int dg    = deg[row];
    float acc = 0.f;

    for (int b = 0; b < dg; b += 64) {
        const int n = min(dg - b, 64);
        const int idx = csr[start + min(b + lane, dg - 1)];
        for (int k = 0; k < n; k += 8) {
            float t[8];
#pragma unroll
            for (int u = 0; u < 8; ++u) {
                const int s = __shfl(idx, min(k + u, n - 1));
                t[u] = Y[(size_t)s * 64 + lane];
            }
            const int m = min(n - k, 8);
#pragma unroll
            for (int u = 0; u < 8; ++u)
                if (u < m) acc += t[u];
        }
    }

    const float v = p0 + p1 + p2 + (acc + self) + cv;
    float mx = v;
#pragma unroll
    for (int off = 32; off > 0; off >>= 1) mx = fmaxf(mx, __shfl_xor(mx, off));
    const float e = __expf(v - mx);
    float s = e;
#pragma unroll
    for (int off = 32; off > 0; off >>= 1) s += __shfl_xor(s, off);
    out[g] = e / s;
}

// ---------------------------------------------------------------------------
// GEMM sub-phase: acc = AccBuf(32x128 fp32 LDS) @ W^T, 128 output cols,
// 1-deep wgt prefetch. (unchanged)
// ---------------------------------------------------------------------------
__device__ __forceinline__ void gemm_tile(
    const float* __restrict__ AccBuf,
    const __bf16* __restrict__ Whi, const __bf16* __restrict__ Wlo,
    const int wn, const int quad, const int l15,
    f32x4 acc[2][2])
{
#pragma unroll
    for (int i = 0; i < 2; ++i)
#pragma unroll
        for (int j = 0; j < 2; ++j) acc[i][j] = (f32x4)(0.0f);

    bf16x8 whA[2], wlA[2], whB[2], wlB[2];
#pragma unroll
    for (int nt = 0; nt < 2; ++nt) {
        const int n = wn + nt * 16 + l15;
        whA[nt] = *(const bf16x8*)(Whi + (size_t)n * 128 + quad * 8);
        wlA[nt] = *(const bf16x8*)(Wlo + (size_t)n * 128 + quad * 8);
    }
#pragma unroll
    for (int ks = 0; ks < 4; ++ks) {
        const int kt = ks * 32 + quad * 8;
        if (ks < 3) {
            const int kn = kt + 32;
#pragma unroll
            for (int nt = 0; nt < 2; ++nt) {
                const int n = wn + nt * 16 + l15;
                whB[nt] = *(const bf16x8*)(Whi + (size_t)n * 128 + kn);
                wlB[nt] = *(const bf16x8*)(Wlo + (size_t)n * 128 + kn);
            }
        }
        bf16x8 ahi[2], alo[2];
#pragma unroll
        for (int mt = 0; mt < 2; ++mt) {
            const float* ap = &AccBuf[(mt * 16 + l15) * ALD + kt];
            const f32x4 p = *(const f32x4*)ap;
            const f32x4 q = *(const f32x4*)(ap + 4);
#pragma unroll
            for (int e = 0; e < 4; ++e) {
                const __bf16 hp = (__bf16)p[e];
                const __bf16 hq = (__bf16)q[e];
                ahi[mt][e]     = hp;
                ahi[mt][e + 4] = hq;
                alo[mt][e]     = (__bf16)(p[e] - (float)hp);
                alo[mt][e + 4] = (__bf16)(q[e] - (float)hq);
            }
        }
#pragma unroll
        for (int mt = 0; mt < 2; ++mt)
#pragma unroll
            for (int nt = 0; nt < 2; ++nt) {
                acc[mt][nt] = __builtin_amdgcn_mfma_f32_16x16x32_bf16(
                    ahi[mt], whA[nt], acc[mt][nt], 0, 0, 0);
                acc[mt][nt] = __builtin_amdgcn_mfma_f32_16x16x32_bf16(
                    ahi[mt], wlA[nt], acc[mt][nt], 0, 0, 0);
                acc[mt][nt] = __builtin_amdgcn_mfma_f32_16x16x32_bf16(
                    alo[mt], whA[nt], acc[mt][nt], 0, 0, 0);
            }
        if (ks < 3) {
#pragma unroll
            for (int nt = 0; nt < 2; ++nt) {
                whA[nt] = whB[nt];
                wlA[nt] = wlB[nt];
            }
        }
    }
}

// ---------------------------------------------------------------------------
// 64-col E-GEMM: acc = AccBuf @ E^T with E [64,128]; each wave computes 16
// cols (wn16 = wave*16). (unchanged)
// ---------------------------------------------------------------------------
__device__ __forceinline__ void gemm_tile64(
    const float* __restrict__ AccBuf,
    const __bf16* __restrict__ Ehi, const __bf16* __restrict__ Elo,
    const int wn16, const int quad, const int l15,
    f32x4 acc[2])
{
    acc[0] = (f32x4)(0.0f);
    acc[1] = (f32x4)(0.0f);

    const int n = wn16 + l15;            // 0..63
    bf16x8 whA, wlA, whB, wlB;
    whA = *(const bf16x8*)(Ehi + (size_t)n * 128 + quad * 8);
    wlA = *(const bf16x8*)(Elo + (size_t)n * 128 + quad * 8);

#pragma unroll
    for (int ks = 0; ks < 4; ++ks) {
        const int kt = ks * 32 + quad * 8;
        if (ks < 3) {
            whB = *(const bf16x8*)(Ehi + (size_t)n * 128 + kt + 32);
            wlB = *(const bf16x8*)(Elo + (size_t)n * 128 + kt + 32);
        }
        bf16x8 ahi[2], alo[2];
#pragma unroll
        for (int mt = 0; mt < 2; ++mt) {
            const float* ap = &AccBuf[(mt * 16 + l15) * ALD + kt];
            const f32x4 p = *(const f32x4*)ap;
            const f32x4 q = *(const f32x4*)(ap + 4);
#pragma unroll
            for (int e = 0; e < 4; ++e) {
                const __bf16 hp = (__bf16)p[e];
                const __bf16 hq = (__bf16)q[e];
                ahi[mt][e]     = hp;
                ahi[mt][e + 4] = hq;
                alo[mt][e]     = (__bf16)(p[e] - (float)hp);
                alo[mt][e + 4] = (__bf16)(q[e] - (float)hq);
            }
        }
#pragma unroll
        for (int mt = 0; mt < 2; ++mt) {
            acc[mt] = __builtin_amdgcn_mfma_f32_16x16x32_bf16(
                ahi[mt], whA, acc[mt], 0, 0, 0);
            acc[mt] = __builtin_amdgcn_mfma_f32_16x16x32_bf16(
                ahi[mt], wlA, acc[mt], 0, 0, 0);
            acc[mt] = __builtin_amdgcn_mfma_f32_16x16x32_bf16(
                alo[mt], whA, acc[mt], 0, 0, 0);
        }
        if (ks < 3) { whA = whB; wlA = wlB; }
    }
}

// ---------------------------------------------------------------------------
// GIN layer with fused output-projection + direct register->global stores.
// (unchanged from round 14)
//   MODE 0: in = x;    h -> Hout fp16; partial = h @ E0^T  (E0 [64,128])
//   MODE 1: in = Aggp; h -> Hout fp16; partial = h @ E1^T
//   MODE 2: in = Aggp; no Hout; z = h @ E2^T (E2 [128,128]);
//           waves 0-1 store partial = z[:,0:64]; waves 2-3 store y2.
// ---------------------------------------------------------------------------
template<int MODE>
__global__ __launch_bounds__(256, 3) void gin_layer(
    const float* __restrict__ in,         // x (MODE 0) or Aggp
    const __bf16* __restrict__ Whi,       // main [128,128]
    const __bf16* __restrict__ Wlo,
    const float* __restrict__ bias,       // [128]
    const __bf16* __restrict__ Ehi,       // E plane
    const __bf16* __restrict__ Elo,
    _Float16* __restrict__ Hout,          // fp16 h (MODE<2)
    float* __restrict__ partial,          // [GN,64] fp32, write-only
    float* __restrict__ y2)               // [GN,64] fp32 (MODE 2)
{
    __shared__ float Acc[32 * ALD];      // 16896 B

    const int tid  = threadIdx.x;
    const int wave = tid >> 6;
    const int lane = tid & 63;
    const int row0 = blockIdx.x * 32;    // 3125*32 == GN exactly
    const int wn   = wave * 32;
    const int quad = lane >> 4;
    const int l15  = lane & 15;
    const int c8   = l15 * 8;

    // ---- Phase A (wave-local): stage own 8 rows into LDS ----
#pragma unroll
    for (int p = 0; p < 2; ++p) {
        const int r = wave * 8 + p * 4 + quad;
        const size_t g = (size_t)(row0 + r) * 128 + c8;
        const f32x4 v0 = *(const f32x4*)(in + g);
        const f32x4 v1 = *(const f32x4*)(in + g + 4);
        *(f32x4*)&Acc[r * ALD + c8]     = v0;
        *(f32x4*)&Acc[r * ALD + c8 + 4] = v1;
    }
    __syncthreads();

    // ---- Phase B1: h = in @ W^T ----
    f32x4 acc1[2][2];
    gemm_tile(Acc, Whi, Wlo, wn, quad, l15, acc1);
    __syncthreads();

    // ---- E1: Acc = h (+bias), fp32 ----
#pragma unroll
    for (int nt = 0; nt < 2; ++nt) {
        const int col = wn + nt * 16 + l15;
        const float b = bias[col];
#pragma unroll
        for (int mt = 0; mt < 2; ++mt)
#pragma unroll
            for (int r4 = 0; r4 < 4; ++r4)
                Acc[(mt * 16 + quad * 4 + r4) * ALD + col] = acc1[mt][nt][r4] + b;
    }
    __syncthreads();

    // ---- Hout fp16 store (MODE<2), from staged Acc ----
    if (MODE < 2) {
#pragma unroll
        for (int p = 0; p < 2; ++p) {
            const int q = tid + p * 256;
            const int r = q >> 4;            // 0..31
            const int g = (q & 15) * 8;
            const float4 a = *(const float4*)&Acc[r * ALD + g];
            const float4 b = *(const float4*)&Acc[r * ALD + g + 4];
            f16x8 o = {(_Float16)a.x, (_Float16)a.y, (_Float16)a.z, (_Float16)a.w,
                       (_Float16)b.x, (_Float16)b.y, (_Float16)b.z, (_Float16)b.w};
            *(f16x8*)&Hout[(size_t)(row0 + r) * 128 + g] = o;
        }
    }

    // ---- Phase B2: z = h @ E^T, DIRECT register stores ----
    if (MODE < 2) {
        f32x4 accE[2];
        gemm_tile64(Acc, Ehi, Elo, wave * 16, quad, l15, accE);
        const int colE = wave * 16 + l15;
#pragma unroll
        for (int mt = 0; mt < 2; ++mt)
#pragma unroll
            for (int r4 = 0; r4 < 4; ++r4)
                partial[(size_t)(row0 + mt * 16 + quad * 4 + r4) * 64 + colE]
                    = accE[mt][r4];
    } else {
        f32x4 acc2[2][2];
        gemm_tile(Acc, Ehi, Elo, wn, quad, l15, acc2);
        float* const dst = (wave < 2) ? partial : y2;
        const int cbase = wn & 63;
#pragma unroll
        for (int nt = 0; nt < 2; ++nt)
#pragma unroll
            for (int mt = 0; mt < 2; ++mt)
#pragma unroll
                for (int r4 = 0; r4 < 4; ++r4)
                    dst[(size_t)(row0 + mt * 16 + quad * 4 + r4) * 64
                        + cbase + nt * 16 + l15] = acc2[mt][nt][r4];
    }
}

// ---------------------------------------------------------------------------
// Remaining CSR kernels (scan_pass3, fill_csr) -- unchanged
// ---------------------------------------------------------------------------
__global__ __launch_bounds__(256) void scan_pass3(int* __restrict__ excl,
                                                  const int* __restrict__ blockOffs,
                                                  int* __restrict__ cursor)
{
    const int i = blockIdx.x * 256 + threadIdx.x;
    if (i >= GN) return;
    const int v = excl[i] + blockOffs[i >> 10];
    excl[i]   = v;
    cursor[i] = v;
}

__global__ __launch_bounds__(256) void fill_csr(const int* __restrict__ src,
                                                const int* __restrict__ dst,
                                                int* __restrict__ cursor,
                                                int* __restrict__ csr)
{
    const int e = blockIdx.x * 256 + threadIdx.x;
    if (e >= GE) return;
    const int pos = atomicAdd(&cursor[dst[e]], 1);
    csr[pos] = src[e];
}

extern "C" void kernel_launch(void* const* d_in, const int* in_sizes, int n_in,
                              void* d_out, int out_size, void* d_ws, size_t ws_size,
                              hipStream_t stream)
{
    const float* x       = (const float*)d_in[0];
    const int*   src     = (const int*)d_in[1];
    const int*   dst     = ((const int*)d_in[1]) + GE;
    const float* W_in    = (const float*)d_in[2];
    const float* b_in    = (const float*)d_in[3];
    const float* W_convs = (const float*)d_in[4];
    const float* b_convs = (const float*)d_in[5];
    const float* W_out   = (const float*)d_in[6];
    const float* b_out   = (const float*)d_in[7];
    float*       out     = (float*)d_out;

    // d_ws layout (~208 MB):
    //   h0|h1 fp16 [GN,128] | Aggp fp32 [GN,128] | p0|p1|p2|y2 fp32 [GN,64]
    //   | cvec | deg | done(4) | row_start | cursor | blockSums | blockOffs |
    //   csr | hi/lo planes (81920 each).
    _Float16* h0   = (_Float16*)d_ws;
    _Float16* h1   = h0 + (size_t)GN * 128;
    float*    Aggp = (float*)(h1 + (size_t)GN * 128);
    float*    p0   = Aggp + (size_t)GN * 128;
    float*    p1   = p0 + (size_t)GN * 64;
    float*    p2   = p1 + (size_t)GN * 64;
    float*    y2   = p2 + (size_t)GN * 64;
    float*    cvec = y2 + (size_t)GN * 64;          // 64 floats (pad 128)
    int*      deg       = (int*)(cvec + 128);
    int*      done      = deg + GN;                  // 4 ints (1 used)
    int*      row_start = done + 4;
    int*      cursor    = row_start + GN;
    int*      blockSums = cursor + GN;
    int*      blockOffs = blockSums + 128;
    int*      csr       = blockOffs + 128;
    __bf16*   Whi       = (__bf16*)(csr + GE);       // 81920 bf16
    __bf16*   Wlo       = Whi + 81920;

    const dim3 blk(256);
    const dim3 gblk(256);
    const int node_blocks   = (GN + 255) / 256;
    const int layer_blocks  = GN / 32;               // 3125 (exact)
    const int gather_blocks = (GN + 3) / 4;

    // --- preamble: zero deg+done; fused count_deg+convert_w; scan1+2; ... ---
    hipMemsetAsync(deg, 0, (GN + 4) * sizeof(int), stream);
    prep_fused<<<EDGE_BLOCKS + CONV_BLOCKS, blk, 0, stream>>>(
        dst, deg, W_in, W_convs, W_out, b_convs + 256, b_out, Whi, Wlo, cvec);
    scan_pass1<<<SCAN_NBLK, blk, 0, stream>>>(deg, row_start, blockSums,
                                              blockOffs, done);
    scan_pass3<<<node_blocks, blk, 0, stream>>>(row_start, blockOffs, cursor);
    fill_csr<<<EDGE_BLOCKS, blk, 0, stream>>>(src, dst, cursor, csr);

    // --- layer 0: x -> h0; p0 = h0 @ Wo0^T ---
    gin_layer<0><<<layer_blocks, gblk, 0, stream>>>(
        x, Whi, Wlo, b_in, Whi + 49152, Wlo + 49152, h0, p0, nullptr);

    // --- layer 1: gather(h0) -> Aggp; Aggp@W1 -> h1; p1 = h1 @ Wo1^T ---
    gather_rows<<<gather_blocks, gblk, 0, stream>>>(
        (const uint*)h0, row_start, deg, csr, Aggp);
    gin_layer<1><<<layer_blocks, gblk, 0, stream>>>(
        Aggp, Whi + 16384, Wlo + 16384, b_convs,
        Whi + 57344, Wlo + 57344, h1, p1, nullptr);

    // --- layer 2: gather(h1) -> Aggp; h2 in LDS only;
    //     p2 = h2 @ Wo2^T; y2 = h2 @ W3p^T ---
    gather_rows<<<gather_blocks, gblk, 0, stream>>>(
        (const uint*)h1, row_start, deg, csr, Aggp);
    gin_layer<2><<<layer_blocks, gblk, 0, stream>>>(
        Aggp, Whi + 32768, Wlo + 32768, b_convs + 128,
        Whi + 65536, Wlo + 65536, nullptr, p2, y2);

    // --- fused: gather(y2) + p0+p1+p2+cvec + softmax -> out ---
    gather_softmax<<<gather_blocks, gblk, 0, stream>>>(
        y2, row_start, deg, csr, p0, p1, p2, cvec, out);
}

// Round 16
// 429.927 us; speedup vs baseline: 1.0298x; 1.0298x over previous
//
#include <hip/hip_runtime.h>
#include <hip/hip_bf16.h>
#include <hip/hip_fp16.h>

#define GN 100000
#define GE 600000
#define SCAN_NBLK 98   // ceil(GN / 1024)
#define ALD 132        // fp32 LDS leading dim: 128 + 4
#define EDGE_BLOCKS ((GE + 255) / 256)      // 2344
#define CONV_BLOCKS ((81984 + 255) / 256)   // 321
#define L0_BLOCKS   (GN / 32)               // 3125

typedef __bf16    bf16x8 __attribute__((ext_vector_type(8)));
typedef _Float16  f16x8  __attribute__((ext_vector_type(8)));
typedef float     f32x4  __attribute__((ext_vector_type(4)));

// ---------------------------------------------------------------------------
// in-register fp32 -> (hi,lo) bf16x8 split; bitwise-identical to convert_w.
// ---------------------------------------------------------------------------
__device__ __forceinline__ void split8(const float* __restrict__ wp,
                                       bf16x8& hi, bf16x8& lo)
{
    const f32x4 a = *(const f32x4*)wp;
    const f32x4 b = *(const f32x4*)(wp + 4);
#pragma unroll
    for (int e = 0; e < 4; ++e) {
        const __bf16 ha = (__bf16)a[e];
        const __bf16 hb = (__bf16)b[e];
        hi[e]     = ha;
        hi[e + 4] = hb;
        lo[e]     = (__bf16)(a[e] - (float)ha);
        lo[e + 4] = (__bf16)(b[e] - (float)hb);
    }
}

// ---------------------------------------------------------------------------
// GEMM sub-phase (bf16 plane weights): acc = AccBuf(32x128 LDS) @ W^T.
// ---------------------------------------------------------------------------
__device__ __forceinline__ void gemm_tile(
    const float* __restrict__ AccBuf,
    const __bf16* __restrict__ Whi, const __bf16* __restrict__ Wlo,
    const int wn, const int quad, const int l15,
    f32x4 acc[2][2])
{
#pragma unroll
    for (int i = 0; i < 2; ++i)
#pragma unroll
        for (int j = 0; j < 2; ++j) acc[i][j] = (f32x4)(0.0f);

    bf16x8 whA[2], wlA[2], whB[2], wlB[2];
#pragma unroll
    for (int nt = 0; nt < 2; ++nt) {
        const int n = wn + nt * 16 + l15;
        whA[nt] = *(const bf16x8*)(Whi + (size_t)n * 128 + quad * 8);
        wlA[nt] = *(const bf16x8*)(Wlo + (size_t)n * 128 + quad * 8);
    }
#pragma unroll
    for (int ks = 0; ks < 4; ++ks) {
        const int kt = ks * 32 + quad * 8;
        if (ks < 3) {
            const int kn = kt + 32;
#pragma unroll
            for (int nt = 0; nt < 2; ++nt) {
                const int n = wn + nt * 16 + l15;
                whB[nt] = *(const bf16x8*)(Whi + (size_t)n * 128 + kn);
                wlB[nt] = *(const bf16x8*)(Wlo + (size_t)n * 128 + kn);
            }
        }
        bf16x8 ahi[2], alo[2];
#pragma unroll
        for (int mt = 0; mt < 2; ++mt) {
            const float* ap = &AccBuf[(mt * 16 + l15) * ALD + kt];
            const f32x4 p = *(const f32x4*)ap;
            const f32x4 q = *(const f32x4*)(ap + 4);
#pragma unroll
            for (int e = 0; e < 4; ++e) {
                const __bf16 hp = (__bf16)p[e];
                const __bf16 hq = (__bf16)q[e];
                ahi[mt][e]     = hp;
                ahi[mt][e + 4] = hq;
                alo[mt][e]     = (__bf16)(p[e] - (float)hp);
                alo[mt][e + 4] = (__bf16)(q[e] - (float)hq);
            }
        }
#pragma unroll
        for (int mt = 0; mt < 2; ++mt)
#pragma unroll
            for (int nt = 0; nt < 2; ++nt) {
                acc[mt][nt] = __builtin_amdgcn_mfma_f32_16x16x32_bf16(
                    ahi[mt], whA[nt], acc[mt][nt], 0, 0, 0);
                acc[mt][nt] = __builtin_amdgcn_mfma_f32_16x16x32_bf16(
                    ahi[mt], wlA[nt], acc[mt][nt], 0, 0, 0);
                acc[mt][nt] = __builtin_amdgcn_mfma_f32_16x16x32_bf16(
                    alo[mt], whA[nt], acc[mt][nt], 0, 0, 0);
            }
        if (ks < 3) {
#pragma unroll
            for (int nt = 0; nt < 2; ++nt) {
                whA[nt] = whB[nt];
                wlA[nt] = wlB[nt];
            }
        }
    }
}

// ---------------------------------------------------------------------------
// GEMM sub-phase, RAW fp32 weights (row pitch `ldw`), in-register split.
// Same math as gemm_tile on pre-converted planes (split8 == convert_w).
// ---------------------------------------------------------------------------
__device__ __forceinline__ void gemm_tile_w32(
    const float* __restrict__ AccBuf,
    const float* __restrict__ W, const int ldw,
    const int wn, const int quad, const int l15,
    f32x4 acc[2][2])
{
#pragma unroll
    for (int i = 0; i < 2; ++i)
#pragma unroll
        for (int j = 0; j < 2; ++j) acc[i][j] = (f32x4)(0.0f);

#pragma unroll
    for (int ks = 0; ks < 4; ++ks) {
        const int kt = ks * 32 + quad * 8;
        bf16x8 wh[2], wl[2];
#pragma unroll
        for (int nt = 0; nt < 2; ++nt) {
            const int n = wn + nt * 16 + l15;
            split8(W + (size_t)n * ldw + kt, wh[nt], wl[nt]);
        }
        bf16x8 ahi[2], alo[2];
#pragma unroll
        for (int mt = 0; mt < 2; ++mt) {
            const float* ap = &AccBuf[(mt * 16 + l15) * ALD + kt];
            const f32x4 p = *(const f32x4*)ap;
            const f32x4 q = *(const f32x4*)(ap + 4);
#pragma unroll
            for (int e = 0; e < 4; ++e) {
                const __bf16 hp = (__bf16)p[e];
                const __bf16 hq = (__bf16)q[e];
                ahi[mt][e]     = hp;
                ahi[mt][e + 4] = hq;
                alo[mt][e]     = (__bf16)(p[e] - (float)hp);
                alo[mt][e + 4] = (__bf16)(q[e] - (float)hq);
            }
        }
#pragma unroll
        for (int mt = 0; mt < 2; ++mt)
#pragma unroll
            for (int nt = 0; nt < 2; ++nt) {
                acc[mt][nt] = __builtin_amdgcn_mfma_f32_16x16x32_bf16(
                    ahi[mt], wh[nt], acc[mt][nt], 0, 0, 0);
                acc[mt][nt] = __builtin_amdgcn_mfma_f32_16x16x32_bf16(
                    ahi[mt], wl[nt], acc[mt][nt], 0, 0, 0);
                acc[mt][nt] = __builtin_amdgcn_mfma_f32_16x16x32_bf16(
                    alo[mt], wh[nt], acc[mt][nt], 0, 0, 0);
            }
    }
}

// ---------------------------------------------------------------------------
// 64-col E-GEMM, RAW fp32 weights (pitch ldw): each wave computes 16 cols.
// ---------------------------------------------------------------------------
__device__ __forceinline__ void gemm_tile64_w32(
    const float* __restrict__ AccBuf,
    const float* __restrict__ E, const int ldw,
    const int wn16, const int quad, const int l15,
    f32x4 acc[2])
{
    acc[0] = (f32x4)(0.0f);
    acc[1] = (f32x4)(0.0f);
    const int n = wn16 + l15;            // 0..63

#pragma unroll
    for (int ks = 0; ks < 4; ++ks) {
        const int kt = ks * 32 + quad * 8;
        bf16x8 wh, wl;
        split8(E + (size_t)n * ldw + kt, wh, wl);
        bf16x8 ahi[2], alo[2];
#pragma unroll
        for (int mt = 0; mt < 2; ++mt) {
            const float* ap = &AccBuf[(mt * 16 + l15) * ALD + kt];
            const f32x4 p = *(const f32x4*)ap;
            const f32x4 q = *(const f32x4*)(ap + 4);
#pragma unroll
            for (int e = 0; e < 4; ++e) {
                const __bf16 hp = (__bf16)p[e];
                const __bf16 hq = (__bf16)q[e];
                ahi[mt][e]     = hp;
                ahi[mt][e + 4] = hq;
                alo[mt][e]     = (__bf16)(p[e] - (float)hp);
                alo[mt][e + 4] = (__bf16)(q[e] - (float)hq);
            }
        }
#pragma unroll
        for (int mt = 0; mt < 2; ++mt) {
            acc[mt] = __builtin_amdgcn_mfma_f32_16x16x32_bf16(
                ahi[mt], wh, acc[mt], 0, 0, 0);
            acc[mt] = __builtin_amdgcn_mfma_f32_16x16x32_bf16(
                ahi[mt], wl, acc[mt], 0, 0, 0);
            acc[mt] = __builtin_amdgcn_mfma_f32_16x16x32_bf16(
                alo[mt], wh, acc[mt], 0, 0, 0);
        }
    }
}

// ---------------------------------------------------------------------------
// FUSED preamble MEGA-kernel, three independent block ranges:
//   [0, EDGE_BLOCKS)                : count_deg (atomicAdd)
//   [EDGE, EDGE+CONV)               : weight planes (Wc0/Wc1/E1/E2+W3p) + cvec
//   [EDGE+CONV, EDGE+CONV+L0_BLOCKS): LAYER 0 (x -> h0, p0) with raw-fp32
//                                     weights split in-register -- no
//                                     dependency on the convert range, so it
//                                     overlaps the CSR atomics.
// Plane layout (81920 entries; W_in/E0 slots unused now):
//   [16384,32768) Wc0 | [32768,49152) Wc1 | [57344,65536) E1 |
//   [65536,81920) E2 (rows 0-63 = Wo2, rows 64-127 = W3p)
// ---------------------------------------------------------------------------
__global__ __launch_bounds__(256, 3) void prep_fused(
    const int* __restrict__ dst, int* __restrict__ deg,
    const float* __restrict__ x,
    const float* __restrict__ Win, const float* __restrict__ Wc,
    const float* __restrict__ Wout,
    const float* __restrict__ bIn,
    const float* __restrict__ b3, const float* __restrict__ bOut,
    __bf16* __restrict__ hi, __bf16* __restrict__ lo,
    float* __restrict__ cvec,
    _Float16* __restrict__ h0, float* __restrict__ p0)
{
    __shared__ float Acc[32 * ALD];      // used only by the layer-0 range

    if (blockIdx.x < EDGE_BLOCKS) {
        const int e = blockIdx.x * 256 + threadIdx.x;
        if (e < GE) atomicAdd(&deg[dst[e]], 1);
        return;
    }
    if (blockIdx.x < EDGE_BLOCKS + CONV_BLOCKS) {
        const int i = (blockIdx.x - EDGE_BLOCKS) * 256 + threadIdx.x;
        const float* W3 = Wc + 32768;                // W_convs[2]
        if (i >= 81984) return;
        if (i >= 81920) {                            // cvec
            const int o = i - 81920;
            float c = bOut[o];
            for (int j = 0; j < 128; ++j)
                c += Wout[o * 512 + 384 + j] * b3[j];
            cvec[o] = c;
            return;
        }
        if (i < 16384) return;                       // W_in slot unused
        if (i >= 49152 && i < 57344) return;         // E0 slot unused
        float v;
        if (i < 49152) {
            v = Wc[i - 16384];                       // Wc0, Wc1
        } else if (i < 65536) {
            const int j = i - 57344;                 // E1
            v = Wout[(j >> 7) * 512 + 128 + (j & 127)];
        } else if (i < 73728) {
            const int j = i - 65536;                 // E2 rows 0-63
            v = Wout[(j >> 7) * 512 + 256 + (j & 127)];
        } else {
            const int j = i - 65536;                 // E2 rows 64-127 = W3p
            const int o = (j >> 7) - 64;
            const int k = j & 127;
            float s = 0.f;
            for (int jj = 0; jj < 128; ++jj)
                s += Wout[o * 512 + 384 + jj] * W3[jj * 128 + k];
            v = s;
        }
        const __bf16 h = (__bf16)v;
        hi[i] = h;
        lo[i] = (__bf16)(v - (float)h);
        return;
    }

    // ---- LAYER 0 range: x -> h0 (fp16); p0 = h0f32 @ Wo0^T ----
    const int tid  = threadIdx.x;
    const int wave = tid >> 6;
    const int lane = tid & 63;
    const int row0 = (blockIdx.x - EDGE_BLOCKS - CONV_BLOCKS) * 32;
    const int wn   = wave * 32;
    const int quad = lane >> 4;
    const int l15  = lane & 15;
    const int c8   = l15 * 8;

#pragma unroll
    for (int p = 0; p < 2; ++p) {
        const int r = wave * 8 + p * 4 + quad;
        const size_t g = (size_t)(row0 + r) * 128 + c8;
        *(f32x4*)&Acc[r * ALD + c8]     = *(const f32x4*)(x + g);
        *(f32x4*)&Acc[r * ALD + c8 + 4] = *(const f32x4*)(x + g + 4);
    }
    __syncthreads();

    f32x4 acc1[2][2];
    gemm_tile_w32(Acc, Win, 128, wn, quad, l15, acc1);
    __syncthreads();

#pragma unroll
    for (int nt = 0; nt < 2; ++nt) {
        const int col = wn + nt * 16 + l15;
        const float b = bIn[col];
#pragma unroll
        for (int mt = 0; mt < 2; ++mt)
#pragma unroll
            for (int r4 = 0; r4 < 4; ++r4)
                Acc[(mt * 16 + quad * 4 + r4) * ALD + col] = acc1[mt][nt][r4] + b;
    }
    __syncthreads();

#pragma unroll
    for (int p = 0; p < 2; ++p) {
        const int q = tid + p * 256;
        const int r = q >> 4;
        const int g = (q & 15) * 8;
        const float4 a = *(const float4*)&Acc[r * ALD + g];
        const float4 b = *(const float4*)&Acc[r * ALD + g + 4];
        f16x8 o = {(_Float16)a.x, (_Float16)a.y, (_Float16)a.z, (_Float16)a.w,
                   (_Float16)b.x, (_Float16)b.y, (_Float16)b.z, (_Float16)b.w};
        *(f16x8*)&h0[(size_t)(row0 + r) * 128 + g] = o;
    }

    f32x4 accE[2];
    gemm_tile64_w32(Acc, Wout, 512, wave * 16, quad, l15, accE);  // E0 = Wout cols 0-127
    const int colE = wave * 16 + l15;
#pragma unroll
    for (int mt = 0; mt < 2; ++mt)
#pragma unroll
        for (int r4 = 0; r4 < 4; ++r4)
            p0[(size_t)(row0 + mt * 16 + quad * 4 + r4) * 64 + colE] = accE[mt][r4];
}

// ---------------------------------------------------------------------------
// scan_pass1 with folded scan_pass2 (round-15, unchanged).
// ---------------------------------------------------------------------------
__global__ __launch_bounds__(256) void scan_pass1(const int* __restrict__ deg,
                                                  int* __restrict__ excl,
                                                  int* __restrict__ blockSums,
                                                  int* __restrict__ blockOffs,
                                                  int* __restrict__ done)
{
    __shared__ int s[256];
    __shared__ bool amLast;
    const int t = threadIdx.x;
    const int base = blockIdx.x * 1024 + t * 4;

    int4 v = make_int4(0, 0, 0, 0);
    if (base + 3 < GN) {
        v = *(const int4*)(deg + base);
    } else {
        if (base + 0 < GN) v.x = deg[base + 0];
        if (base + 1 < GN) v.y = deg[base + 1];
        if (base + 2 < GN) v.z = deg[base + 2];
        if (base + 3 < GN) v.w = deg[base + 3];
    }
    const int mysum = v.x + v.y + v.z + v.w;
    s[t] = mysum;
    __syncthreads();
    for (int off = 1; off < 256; off <<= 1) {
        const int val = (t >= off) ? s[t - off] : 0;
        __syncthreads();
        s[t] += val;
        __syncthreads();
    }
    int4 o;
    o.x = s[t] - mysum;
    o.y = o.x + v.x;
    o.z = o.y + v.y;
    o.w = o.z + v.z;
    if (base + 3 < GN) {
        *(int4*)(excl + base) = o;
    } else {
        if (base + 0 < GN) excl[base + 0] = o.x;
        if (base + 1 < GN) excl[base + 1] = o.y;
        if (base + 2 < GN) excl[base + 2] = o.z;
        if (base + 3 < GN) excl[base + 3] = o.w;
    }
    if (t == 255) blockSums[blockIdx.x] = s[255];

    __threadfence();
    if (t == 0)
        amLast = (atomicAdd(done, 1) == SCAN_NBLK - 1);
    __syncthreads();
    if (amLast) {
        __threadfence();
        const int bv = (t < SCAN_NBLK) ? blockSums[t] : 0;
        s[t] = (t < 128) ? bv : 0;
        __syncthreads();
        for (int off = 1; off < 128; off <<= 1) {
            const int val = (t >= off && t < 128) ? s[t - off] : 0;
            __syncthreads();
            if (t < 128) s[t] += val;
            __syncthreads();
        }
        if (t < SCAN_NBLK) blockOffs[t] = s[t] - bv;
    }
}

// ---------------------------------------------------------------------------
// Streaming gather (unchanged): Aggp[row] = sum(neighbors) + h[row].
// ---------------------------------------------------------------------------
__global__ __launch_bounds__(256, 8) void gather_rows(
    const uint* __restrict__ Hw,
    const int* __restrict__ row_start,
    const int* __restrict__ deg,
    const int* __restrict__ csr,
    float* __restrict__ Aggp)
{
    const int wave = threadIdx.x >> 6;
    const int lane = threadIdx.x & 63;
    const int row  = blockIdx.x * 4 + wave;
    if (row >= GN) return;

    const uint self = Hw[(size_t)row * 64 + lane];
    const int start = row_start[row];
    const int dg    = deg[row];
    float2 acc = make_float2(0.f, 0.f);

    for (int b = 0; b < dg; b += 64) {
        const int n = min(dg - b, 64);
        const int idx = csr[start + min(b + lane, dg - 1)];
        for (int k = 0; k < n; k += 8) {
            uint t[8];
#pragma unroll
            for (int u = 0; u < 8; ++u) {
                const int s = __shfl(idx, min(k + u, n - 1));
                t[u] = Hw[(size_t)s * 64 + lane];
            }
            const int m = min(n - k, 8);
#pragma unroll
            for (int u = 0; u < 8; ++u) {
                if (u < m) {
                    union { uint uu; _Float16 h[2]; } cv;
                    cv.uu = t[u];
                    acc.x += (float)cv.h[0];
                    acc.y += (float)cv.h[1];
                }
            }
        }
    }

    union { uint uu; _Float16 h[2]; } sv;
    sv.uu = self;
    acc.x += (float)sv.h[0];
    acc.y += (float)sv.h[1];

    *(float2*)&Aggp[(size_t)row * 128 + lane * 2] = acc;
}

// ---------------------------------------------------------------------------
// FUSED final (unchanged): gather y2 + p0+p1+p2+cvec + softmax -> out.
// ---------------------------------------------------------------------------
__global__ __launch_bounds__(256, 8) void gather_softmax(
    const float* __restrict__ Y,
    const int* __restrict__ row_start,
    const int* __restrict__ deg,
    const int* __restrict__ csr,
    const float* __restrict__ P0,
    const float* __restrict__ P1,
    const float* __restrict__ P2,
    const float* __restrict__ cvec,
    float* __restrict__ out)
{
    const int wave = threadIdx.x >> 6;
    const int lane = threadIdx.x & 63;
    const int row  = blockIdx.x * 4 + wave;
    if (row >= GN) return;

    const size_t g = (size_t)row * 64 + lane;
    const float p0 = P0[g];
    const float p1 = P1[g];
    const float p2 = P2[g];
    const float self = Y[g];
    const float cv = cvec[lane];

    const int start = row_start[row];
    const int dg    = deg[row];
    float acc = 0.f;

    for (int b = 0; b < dg; b += 64) {
        const int n = min(dg - b, 64);
        const int idx = csr[start + min(b + lane, dg - 1)];
        for (int k = 0; k < n; k += 8) {
            float t[8];
#pragma unroll
            for (int u = 0; u < 8; ++u) {
                const int s = __shfl(idx, min(k + u, n - 1));
                t[u] = Y[(size_t)s * 64 + lane];
            }
            const int m = min(n - k, 8);
#pragma unroll
            for (int u = 0; u < 8; ++u)
                if (u < m) acc += t[u];
        }
    }

    const float v = p0 + p1 + p2 + (acc + self) + cv;
    float mx = v;
#pragma unroll
    for (int off = 32; off > 0; off >>= 1) mx = fmaxf(mx, __shfl_xor(mx, off));
    const float e = __expf(v - mx);
    float s = e;
#pragma unroll
    for (int off = 32; off > 0; off >>= 1) s += __shfl_xor(s, off);
    out[g] = e / s;
}

// ---------------------------------------------------------------------------
// 64-col E-GEMM on bf16 planes (unchanged).
// ---------------------------------------------------------------------------
__device__ __forceinline__ void gemm_tile64(
    const float* __restrict__ AccBuf,
    const __bf16* __restrict__ Ehi, const __bf16* __restrict__ Elo,
    const int wn16, const int quad, const int l15,
    f32x4 acc[2])
{
    acc[0] = (f32x4)(0.0f);
    acc[1] = (f32x4)(0.0f);

    const int n = wn16 + l15;
    bf16x8 whA, wlA, whB, wlB;
    whA = *(const bf16x8*)(Ehi + (size_t)n * 128 + quad * 8);
    wlA = *(const bf16x8*)(Elo + (size_t)n * 128 + quad * 8);

#pragma unroll
    for (int ks = 0; ks < 4; ++ks) {
        const int kt = ks * 32 + quad * 8;
        if (ks < 3) {
            whB = *(const bf16x8*)(Ehi + (size_t)n * 128 + kt + 32);
            wlB = *(const bf16x8*)(Elo + (size_t)n * 128 + kt + 32);
        }
        bf16x8 ahi[2], alo[2];
#pragma unroll
        for (int mt = 0; mt < 2; ++mt) {
            const float* ap = &AccBuf[(mt * 16 + l15) * ALD + kt];
            const f32x4 p = *(const f32x4*)ap;
            const f32x4 q = *(const f32x4*)(ap + 4);
#pragma unroll
            for (int e = 0; e < 4; ++e) {
                const __bf16 hp = (__bf16)p[e];
                const __bf16 hq = (__bf16)q[e];
                ahi[mt][e]     = hp;
                ahi[mt][e + 4] = hq;
                alo[mt][e]     = (__bf16)(p[e] - (float)hp);
                alo[mt][e + 4] = (__bf16)(q[e] - (float)hq);
            }
        }
#pragma unroll
        for (int mt = 0; mt < 2; ++mt) {
            acc[mt] = __builtin_amdgcn_mfma_f32_16x16x32_bf16(
                ahi[mt], whA, acc[mt], 0, 0, 0);
            acc[mt] = __builtin_amdgcn_mfma_f32_16x16x32_bf16(
                ahi[mt], wlA, acc[mt], 0, 0, 0);
            acc[mt] = __builtin_amdgcn_mfma_f32_16x16x32_bf16(
                alo[mt], whA, acc[mt], 0, 0, 0);
        }
        if (ks < 3) { whA = whB; wlA = wlB; }
    }
}

// ---------------------------------------------------------------------------
// GIN layer (modes 1,2 only now; layer 0 lives in prep_fused).
//   MODE 1: in = Aggp; h -> Hout fp16; partial = h @ E1^T
//   MODE 2: in = Aggp; no Hout; z = h @ E2^T (E2 [128,128]);
//           waves 0-1 store partial = z[:,0:64]; waves 2-3 store y2.
// ---------------------------------------------------------------------------
template<int MODE>
__global__ __launch_bounds__(256, 3) void gin_layer(
    const float* __restrict__ in,
    const __bf16* __restrict__ Whi,
    const __bf16* __restrict__ Wlo,
    const float* __restrict__ bias,
    const __bf16* __restrict__ Ehi,
    const __bf16* __restrict__ Elo,
    _Float16* __restrict__ Hout,
    float* __restrict__ partial,
    float* __restrict__ y2)
{
    __shared__ float Acc[32 * ALD];

    const int tid  = threadIdx.x;
    const int wave = tid >> 6;
    const int lane = tid & 63;
    const int row0 = blockIdx.x * 32;
    const int wn   = wave * 32;
    const int quad = lane >> 4;
    const int l15  = lane & 15;
    const int c8   = l15 * 8;

#pragma unroll
    for (int p = 0; p < 2; ++p) {
        const int r = wave * 8 + p * 4 + quad;
        const size_t g = (size_t)(row0 + r) * 128 + c8;
        *(f32x4*)&Acc[r * ALD + c8]     = *(const f32x4*)(in + g);
        *(f32x4*)&Acc[r * ALD + c8 + 4] = *(const f32x4*)(in + g + 4);
    }
    __syncthreads();

    f32x4 acc1[2][2];
    gemm_tile(Acc, Whi, Wlo, wn, quad, l15, acc1);
    __syncthreads();

#pragma unroll
    for (int nt = 0; nt < 2; ++nt) {
        const int col = wn + nt * 16 + l15;
        const float b = bias[col];
#pragma unroll
        for (int mt = 0; mt < 2; ++mt)
#pragma unroll
            for (int r4 = 0; r4 < 4; ++r4)
                Acc[(mt * 16 + quad * 4 + r4) * ALD + col] = acc1[mt][nt][r4] + b;
    }
    __syncthreads();

    if (MODE < 2) {
#pragma unroll
        for (int p = 0; p < 2; ++p) {
            const int q = tid + p * 256;
            const int r = q >> 4;
            const int g = (q & 15) * 8;
            const float4 a = *(const float4*)&Acc[r * ALD + g];
            const float4 b = *(const float4*)&Acc[r * ALD + g + 4];
            f16x8 o = {(_Float16)a.x, (_Float16)a.y, (_Float16)a.z, (_Float16)a.w,
                       (_Float16)b.x, (_Float16)b.y, (_Float16)b.z, (_Float16)b.w};
            *(f16x8*)&Hout[(size_t)(row0 + r) * 128 + g] = o;
        }
    }

    if (MODE < 2) {
        f32x4 accE[2];
        gemm_tile64(Acc, Ehi, Elo, wave * 16, quad, l15, accE);
        const int colE = wave * 16 + l15;
#pragma unroll
        for (int mt = 0; mt < 2; ++mt)
#pragma unroll
            for (int r4 = 0; r4 < 4; ++r4)
                partial[(size_t)(row0 + mt * 16 + quad * 4 + r4) * 64 + colE]
                    = accE[mt][r4];
    } else {
        f32x4 acc2[2][2];
        gemm_tile(Acc, Ehi, Elo, wn, quad, l15, acc2);
        float* const dst = (wave < 2) ? partial : y2;
        const int cbase = wn & 63;
#pragma unroll
        for (int nt = 0; nt < 2; ++nt)
#pragma unroll
            for (int mt = 0; mt < 2; ++mt)
#pragma unroll
                for (int r4 = 0; r4 < 4; ++r4)
                    dst[(size_t)(row0 + mt * 16 + quad * 4 + r4) * 64
                        + cbase + nt * 16 + l15] = acc2[mt][nt][r4];
    }
}

// ---------------------------------------------------------------------------
// Remaining CSR kernels (unchanged)
// ---------------------------------------------------------------------------
__global__ __launch_bounds__(256) void scan_pass3(int* __restrict__ excl,
                                                  const int* __restrict__ blockOffs,
                                                  int* __restrict__ cursor)
{
    const int i = blockIdx.x * 256 + threadIdx.x;
    if (i >= GN) return;
    const int v = excl[i] + blockOffs[i >> 10];
    excl[i]   = v;
    cursor[i] = v;
}

__global__ __launch_bounds__(256) void fill_csr(const int* __restrict__ src,
                                                const int* __restrict__ dst,
                                                int* __restrict__ cursor,
                                                int* __restrict__ csr)
{
    const int e = blockIdx.x * 256 + threadIdx.x;
    if (e >= GE) return;
    const int pos = atomicAdd(&cursor[dst[e]], 1);
    csr[pos] = src[e];
}

extern "C" void kernel_launch(void* const* d_in, const int* in_sizes, int n_in,
                              void* d_out, int out_size, void* d_ws, size_t ws_size,
                              hipStream_t stream)
{
    const float* x       = (const float*)d_in[0];
    const int*   src     = (const int*)d_in[1];
    const int*   dst     = ((const int*)d_in[1]) + GE;
    const float* W_in    = (const float*)d_in[2];
    const float* b_in    = (const float*)d_in[3];
    const float* W_convs = (const float*)d_in[4];
    const float* b_convs = (const float*)d_in[5];
    const float* W_out   = (const float*)d_in[6];
    const float* b_out   = (const float*)d_in[7];
    float*       out     = (float*)d_out;

    _Float16* h0   = (_Float16*)d_ws;
    _Float16* h1   = h0 + (size_t)GN * 128;
    float*    Aggp = (float*)(h1 + (size_t)GN * 128);
    float*    p0   = Aggp + (size_t)GN * 128;
    float*    p1   = p0 + (size_t)GN * 64;
    float*    p2   = p1 + (size_t)GN * 64;
    float*    y2   = p2 + (size_t)GN * 64;
    float*    cvec = y2 + (size_t)GN * 64;          // 64 floats (pad 128)
    int*      deg       = (int*)(cvec + 128);
    int*      done      = deg + GN;                  // 4 ints (1 used)
    int*      row_start = done + 4;
    int*      cursor    = row_start + GN;
    int*      blockSums = cursor + GN;
    int*      blockOffs = blockSums + 128;
    int*      csr       = blockOffs + 128;
    __bf16*   Whi       = (__bf16*)(csr + GE);       // 81920 bf16
    __bf16*   Wlo       = Whi + 81920;

    const dim3 blk(256);
    const dim3 gblk(256);
    const int node_blocks   = (GN + 255) / 256;
    const int layer_blocks  = GN / 32;               // 3125
    const int gather_blocks = (GN + 3) / 4;

    // --- preamble: zero deg+done; MEGA prep (count_deg || convert || L0) ---
    hipMemsetAsync(deg, 0, (GN + 4) * sizeof(int), stream);
    prep_fused<<<EDGE_BLOCKS + CONV_BLOCKS + L0_BLOCKS, blk, 0, stream>>>(
        dst, deg, x, W_in, W_convs, W_out, b_in, b_convs + 256, b_out,
        Whi, Wlo, cvec, h0, p0);
    scan_pass1<<<SCAN_NBLK, blk, 0, stream>>>(deg, row_start, blockSums,
                                              blockOffs, done);
    scan_pass3<<<node_blocks, blk, 0, stream>>>(row_start, blockOffs, cursor);
    fill_csr<<<EDGE_BLOCKS, blk, 0, stream>>>(src, dst, cursor, csr);

    // --- layer 1: gather(h0) -> Aggp; Aggp@W1 -> h1; p1 = h1 @ Wo1^T ---
    gather_rows<<<gather_blocks, gblk, 0, stream>>>(
        (const uint*)h0, row_start, deg, csr, Aggp);
    gin_layer<1><<<layer_blocks, gblk, 0, stream>>>(
        Aggp, Whi + 16384, Wlo + 16384, b_convs,
        Whi + 57344, Wlo + 57344, h1, p1, nullptr);

    // --- layer 2: gather(h1) -> Aggp; h2 in LDS only;
    //     p2 = h2 @ Wo2^T; y2 = h2 @ W3p^T ---
    gather_rows<<<gather_blocks, gblk, 0, stream>>>(
        (const uint*)h1, row_start, deg, csr, Aggp);
    gin_layer<2><<<layer_blocks, gblk, 0, stream>>>(
        Aggp, Whi + 32768, Wlo + 32768, b_convs + 128,
        Whi + 65536, Wlo + 65536, nullptr, p2, y2);

    // --- fused: gather(y2) + p0+p1+p2+cvec + softmax -> out ---
    gather_softmax<<<gather_blocks, gblk, 0, stream>>>(
        y2, row_start, deg, csr, p0, p1, p2, cvec, out);
}